// Round 16
// baseline (466.856 us; speedup 1.0000x reference)
//
#include <hip/hip_runtime.h>
#include <math.h>

// Radial NUFFT + Pipe-Menon density compensation, MI355X (gfx950).
// bf16 MFMA (16x16x32), 2-term hi/lo split (3 products). Round 30 = r29
// (session best 456.5us) + adj PHASE-MERGE: 2 chunks per barrier round.
// All six prior adj schedule variants kept 1 chunk/phase -- 24 MFMA
// (~150cyc) vs ~600-900cyc of fixed per-phase cost (2 barriers + vmcnt +
// frag-read latency): the m233 regime where fixed cost dominates. Now:
// 4 chunk-buffers (64 KB LDS exactly), stage PAIR p+1 (8 g2l16) while
// computing pair p (48 MFMA), vmcnt(8) waits only the oldest pair,
// barrier count halves (36 -> 18 of each). WAR: stage-pair p+1 writes
// bufs (2p+2)&3,(2p+3)&3, last read in phase p-1, drained at lgkm(0)
// before barrier#2(p-1) < stage issue -> safe (r23 proof shape).
// Cost: 3->2 blocks/CU (LDS) + ~64 VGPR for the doubled fragment set.

#define MTOT 36864      // N_SHOTS*N_SAMPLES == NPIX*NPIX
#define NPIX 192
#define SPLITS 128
#define GRP 64                  // split-groups: block g covers splits {g, g+64}
#define NCH 36                  // 2 splits x 18 chunks of 16 m
#define PG 64                   // privatized partial images (one per group)

typedef __attribute__((ext_vector_type(8))) short s16x8;
typedef __attribute__((ext_vector_type(4))) float f32x4;
typedef __attribute__((ext_vector_type(4))) unsigned u32x4;

__device__ __forceinline__ f32x4 mfma_bf16(u32x4 a, u32x4 b, f32x4 c) {
    return __builtin_amdgcn_mfma_f32_16x16x32_bf16(
        __builtin_bit_cast(s16x8, a), __builtin_bit_cast(s16x8, b), c, 0, 0, 0);
}

// async 16B/lane global->LDS (DMA); LDS dest = wave-uniform base + lane*16.
__device__ __forceinline__ void g2l16(const void* g, void* l) {
    __builtin_amdgcn_global_load_lds(
        (const __attribute__((address_space(1))) void*)g,
        (__attribute__((address_space(3))) void*)l, 16, 0, 0);
}

// Split (a,b) into packed bf16 pairs: hi = (bf16(a) | bf16(b)<<16), lo = residuals.
__device__ __forceinline__ void split_pk(float a, float b, unsigned &hi, unsigned &lo) {
    const unsigned ua = __float_as_uint(a), ub = __float_as_uint(b);
    const unsigned ha = (ua + 0x8000u) & 0xffff0000u;
    const unsigned hb = (ub + 0x8000u) & 0xffff0000u;
    hi = (ha >> 16) | hb;
    const float la = a - __uint_as_float(ha);
    const float lb = b - __uint_as_float(hb);
    lo = ((__float_as_uint(la) + 0x8000u) >> 16) |
         ((__float_as_uint(lb) + 0x8000u) & 0xffff0000u);
}

// k split into 12-bit hi + residual so kh*p (p integer, |p|<=96) is EXACT in fp32.
__device__ __forceinline__ void ksplit(float k, float &kh, float &kl) {
    kh = __uint_as_float(__float_as_uint(k) & 0xfffff000u);
    kl = k - kh;
}
__device__ __forceinline__ float redphase(float kh, float kl, float p) {
    float r = kh * p;
    r -= rintf(r);
    r = fmaf(kl, p, r);
    return r;                   // revolutions, |r| <= ~0.512
}
__device__ __forceinline__ unsigned rot16(unsigned v) {
    return __builtin_amdgcn_alignbit(v, v, 16);
}
__device__ __forceinline__ int swz(int c) {        // bank swizzle (r10-verified)
    return ((c ^ (c >> 2)) & 3) << 2;
}

// ---------------------------------------------------------------------------
// Precompute packed B phasor (cos, -sin) hi/lo, chunk-contiguous + swizzled:
// PS[mc][plane][c(192)][mi^swz(c)]  (r10-verified layout).
__global__ void precompP_k(const float* __restrict__ traj, const int comp,
                           unsigned* __restrict__ PS) {
    const int m = blockIdx.x * 256 + threadIdx.x;
    const int c = blockIdx.y;
    float kh, kl; ksplit(traj[2 * m + comp], kh, kl);
    const float ph = redphase(kh, kl, (float)(c - 96));
    const float co = __builtin_amdgcn_cosf(ph);
    const float si = __builtin_amdgcn_sinf(ph);
    unsigned h, l; split_pk(co, -si, h, l);
    const int mc = m >> 4, mi = (m & 15) ^ swz(c);
    PS[(size_t)mc * 6144 + c * 16 + mi]        = h;
    PS[(size_t)mc * 6144 + 3072 + c * 16 + mi] = l;
}

// E[m,x] = conj(A[m,x]) * d[m], packed bf16 hi/lo, same swizzled layout.
__global__ void ebuild_k(const float* __restrict__ traj,
                         const float* __restrict__ dr, const float* __restrict__ di,
                         unsigned* __restrict__ ES) {
    const int m = blockIdx.x * 256 + threadIdx.x;
    const int c = blockIdx.y;                        // x coordinate
    float kh, kl; ksplit(traj[2 * m], kh, kl);
    const float ph = redphase(kh, kl, (float)(c - 96));
    const float co = __builtin_amdgcn_cosf(ph);
    const float si = __builtin_amdgcn_sinf(ph);
    const float dr_ = dr[m], di_ = di[m];
    const float Er = co * dr_ - si * di_;
    const float Ei = co * di_ + si * dr_;
    unsigned h, l; split_pk(Er, Ei, h, l);
    const int mc = m >> 4, mi = (m & 15) ^ swz(c);
    ES[(size_t)mc * 6144 + c * 16 + mi]        = h;
    ES[(size_t)mc * 6144 + 3072 + c * 16 + mi] = l;
}

__global__ void winit_k(float* __restrict__ wr, float* __restrict__ wi) {
    const int m = blockIdx.x * 256 + threadIdx.x;
    wr[m] = 1.f; wi[m] = 0.f;
}

// ---------------------------------------------------------------------------
// Adjoint pure GEMM, 2-chunk phases: outP[g][x,y] =
// sum_{m in splits g,g+64} E[m,x]*conj(B[m,y]).
// 576 blocks (64 groups x 9 tiles) of 4 waves; block owns a 64x64 tile of
// image g EXCLUSIVELY -> plain stores, zero atomics. 4 chunk-buffers
// (64 KB), stage pair p+1 while computing pair p, vmcnt(8) waits only the
// oldest pair, 18 barrier rounds instead of 36.
__global__ __launch_bounds__(256) void adj_gemm_k(
    const unsigned* __restrict__ ES, const unsigned* __restrict__ BS,
    float* __restrict__ outP)
{
    __shared__ unsigned sAB[4][4096];              // 64 KB, buf = chunk & 3
    const int tid = threadIdx.x;
    const int lane = tid & 63, wid = tid >> 6;     // wid 0..3
    const int l15 = lane & 15, qd = lane >> 4;
    const int L = blockIdx.x;                      // 0..575, XCD swizzle
    const int xcd = L & 7, j = L >> 3;             // j 0..71
    const int g = xcd * (GRP / 8) + j / 9;         // split-group 0..63
    const int tile = j % 9;
    const int bx = tile % 3, by = tile / 3;
    const int wi = wid & 1, wj = wid >> 1;
    const int x0 = bx * 64 + wi * 32, y0 = by * 64 + wj * 32;
    float* outRe = outP + (size_t)g * (2 * MTOT);
    float* outIm = outRe + MTOT;

    f32x4 accRe[2][2], accIm[2][2];
    #pragma unroll
    for (int i = 0; i < 2; ++i)
        #pragma unroll
        for (int j2 = 0; j2 < 2; ++j2) {
            accRe[i][j2] = (f32x4){0.f, 0.f, 0.f, 0.f};
            accIm[i][j2] = (f32x4){0.f, 0.f, 0.f, 0.f};
        }

    // staging: chunk c of this block = split (g + 64*(c>=18)), local chunk c%18
    const size_t g18 = (size_t)g * 18;
    const int exo = bx * 1024 + tid * 4;           // E rows [bx*64..+64)
    const int byo = by * 1024 + tid * 4;           // B rows [by*64..+64)
    #define STAGE(c)                                                       \
    {                                                                      \
        const int buf_ = (c) & 3;                                          \
        const size_t id_ = (g18 + (c) + (((c) >= 18) ? 1134 : 0)) * 6144; \
        const unsigned* E0_ = ES + id_;                                    \
        const unsigned* B0_ = BS + id_;                                    \
        g2l16(E0_ + exo,        &sAB[buf_][tid * 4]);                      \
        g2l16(E0_ + 3072 + exo, &sAB[buf_][1024 + tid * 4]);               \
        g2l16(B0_ + byo,        &sAB[buf_][2048 + tid * 4]);               \
        g2l16(B0_ + 3072 + byo, &sAB[buf_][3072 + tid * 4]);               \
    }

    // fragment LDS word offsets within a buffer (local coord; swz(local)==swz(global))
    int eoff[2], boff[2];
    #pragma unroll
    for (int t = 0; t < 2; ++t) {
        const int cE = wi * 32 + t * 16 + l15;     // local x coord 0..63
        eoff[t] = cE * 16 + ((qd ^ ((cE ^ (cE >> 2)) & 3)) << 2);
        const int cB = wj * 32 + t * 16 + l15;     // local y coord 0..63
        boff[t] = 2048 + cB * 16 + ((qd ^ ((cB ^ (cB >> 2)) & 3)) << 2);
    }

    STAGE(0);                                      // prologue: pair 0
    STAGE(1);

    for (int p = 0; p < NCH / 2; ++p) {            // 18 phases of 2 chunks
        const int c0 = 2 * p, c1 = c0 + 1;
        if (c0 + 2 < NCH) {                        // stage pair p+1
            STAGE(c0 + 2);
            STAGE(c1 + 2);
            // outstanding: pair p (8), pair p+1 (8); wait oldest 8 (pair p)
            asm volatile("s_waitcnt vmcnt(8)" ::: "memory");
        } else {
            asm volatile("s_waitcnt vmcnt(0)" ::: "memory");
        }
        __builtin_amdgcn_s_barrier();              // bufs c0,c1 ready block-wide

        const unsigned* sb0 = &sAB[c0 & 3][0];
        const unsigned* sb1 = &sAB[c1 & 3][0];
        u32x4 Eh[2][2], El[2][2], PhA[2][2], PlA[2][2];   // [chunk][t]
        #pragma unroll
        for (int t = 0; t < 2; ++t) {
            Eh[0][t]  = *(const u32x4*)(sb0 + eoff[t]);
            El[0][t]  = *(const u32x4*)(sb0 + 1024 + eoff[t]);
            PhA[0][t] = *(const u32x4*)(sb0 + boff[t]);
            PlA[0][t] = *(const u32x4*)(sb0 + 1024 + boff[t]);
            Eh[1][t]  = *(const u32x4*)(sb1 + eoff[t]);
            El[1][t]  = *(const u32x4*)(sb1 + 1024 + eoff[t]);
            PhA[1][t] = *(const u32x4*)(sb1 + boff[t]);
            PlA[1][t] = *(const u32x4*)(sb1 + 1024 + boff[t]);
        }
        asm volatile("s_waitcnt lgkmcnt(0)" ::: "memory");
        __builtin_amdgcn_sched_barrier(0);         // rule 18: pin MFMAs below
        __builtin_amdgcn_s_barrier();              // all waves done reading

        #pragma unroll
        for (int cc = 0; cc < 2; ++cc) {
            #pragma unroll
            for (int sj = 0; sj < 2; ++sj) {
                const u32x4 Ph = PhA[cc][sj], Pl = PlA[cc][sj];
                u32x4 Qh, Ql;
                #pragma unroll
                for (int r = 0; r < 4; ++r) {
                    Qh[r] = rot16(Ph[r]) ^ 0x00008000u;               // (sb, cb)
                    Ql[r] = rot16(Pl[r]) ^ 0x00008000u;
                }
                #pragma unroll
                for (int si = 0; si < 2; ++si) {
                    accRe[si][sj] = mfma_bf16(Eh[cc][si], Ph, accRe[si][sj]);
                    accRe[si][sj] = mfma_bf16(Eh[cc][si], Pl, accRe[si][sj]);
                    accRe[si][sj] = mfma_bf16(El[cc][si], Ph, accRe[si][sj]);
                    accIm[si][sj] = mfma_bf16(Eh[cc][si], Qh, accIm[si][sj]);
                    accIm[si][sj] = mfma_bf16(Eh[cc][si], Ql, accIm[si][sj]);
                    accIm[si][sj] = mfma_bf16(El[cc][si], Qh, accIm[si][sj]);
                }
            }
        }
    }
    #undef STAGE

    // epilogue: PLAIN stores -- block exclusively owns tile (g, x0.., y0..)
    #pragma unroll
    for (int si = 0; si < 2; ++si)
        #pragma unroll
        for (int sj = 0; sj < 2; ++sj)
            #pragma unroll
            for (int rg = 0; rg < 4; ++rg) {
                const int x = x0 + si * 16 + qd * 4 + rg;   // C/D row
                const int y = y0 + sj * 16 + l15;           // C/D col
                outRe[x * NPIX + y] = accRe[si][sj][rg];
                outIm[x * NPIX + y] = accIm[si][sj][rg];
            }
}

// ---------------------------------------------------------------------------
// fwdq: q[m] = sum_x A[m,x] * (sum_y B[m,y]*g[x,y]).  r27 form: B-phasors
// gathered from BS (no sincos chain), single barrier per chunk, reg-staged
// double buffer. Ph=W^0x80000000 (exact), Qh=rot16(W).
__device__ __forceinline__ void fw_stage_load(const unsigned* __restrict__ Ghi,
                                              const unsigned* __restrict__ Glo,
                                              int tid, int koff, u32x4 st[3]) {
    #pragma unroll
    for (int j = 0; j < 3; ++j) {
        const int li = tid + j * 576;
        if (li < 1536) {
            const int row = li >> 3, pl = (li >> 2) & 1, qt = li & 3;
            const unsigned* src = pl ? Glo : Ghi;
            st[j] = *(const u32x4*)(src + row * 192 + koff + qt * 4);
        }
    }
}
__device__ __forceinline__ void fw_stage_write(unsigned* sb, int tid, const u32x4 st[3]) {
    #pragma unroll
    for (int j = 0; j < 3; ++j) {
        const int li = tid + j * 576;
        if (li < 1536) {
            const int row = li >> 3, pl = (li >> 2) & 1, qt = li & 3;
            *(u32x4*)(sb + pl * 3840 + row * 20 + qt * 4) = st[j];
        }
    }
}

__global__ __launch_bounds__(576) void fwdq_k(
    const float* __restrict__ traj, const unsigned* __restrict__ BS,
    const unsigned* __restrict__ Ghi, const unsigned* __restrict__ Glo,
    float* __restrict__ wre, float* __restrict__ wim,
    const int mode,
    float* __restrict__ qre, float* __restrict__ qim)
{
    __shared__ unsigned sG[2][2 * 3840];   // 60 KB
    const int tid = threadIdx.x;
    const int lane = tid & 63, wid = tid >> 6;         // wid 0..8
    const int l15 = lane & 15, q = lane >> 4;
    const int mc = blockIdx.x * 9 + wid;
    const int m = mc * 16 + l15;
    const float kx = traj[2 * m];
    float kxh, kxl;
    ksplit(kx, kxh, kxl);

    f32x4 tre[12], tim[12];
    #pragma unroll
    for (int i = 0; i < 12; ++i) {
        tre[i] = (f32x4){0.f, 0.f, 0.f, 0.f};
        tim[i] = (f32x4){0.f, 0.f, 0.f, 0.f};
    }

    // B-phasor gather offsets within the wave's BS mc-slice
    const unsigned* Bm = BS + (size_t)mc * 6144;
    int od[4];
    #pragma unroll
    for (int r = 0; r < 4; ++r)
        od[r] = (q * 4 + r) * 16 + (l15 ^ (((r ^ q) & 3) << 2));

    unsigned Wh[4], Wl[4];
    #pragma unroll
    for (int r = 0; r < 4; ++r) { Wh[r] = Bm[od[r]]; Wl[r] = Bm[3072 + od[r]]; }

    u32x4 st[3];
    fw_stage_load(Ghi, Glo, tid, 0, st);
    fw_stage_write(&sG[0][0], tid, st);
    __syncthreads();

    for (int ch = 0; ch < 12; ++ch) {
        if (ch < 11) fw_stage_load(Ghi, Glo, tid, (ch + 1) * 16, st);

        // phasors from precomputed W = (cos, -sin):
        u32x4 Ph, Pl, Qh, Ql;
        #pragma unroll
        for (int r = 0; r < 4; ++r) {
            Ph[r] = Wh[r] ^ 0x80000000u;     // (cos,  sin)
            Pl[r] = Wl[r] ^ 0x80000000u;
            Qh[r] = rot16(Wh[r]);            // (-sin, cos)
            Ql[r] = rot16(Wl[r]);
        }
        // prefetch next chunk's phasor words (use-distance = 72 MFMAs)
        unsigned Nh[4], Nl[4];
        if (ch < 11) {
            const unsigned* Bn = Bm + (ch + 1) * 256;
            #pragma unroll
            for (int r = 0; r < 4; ++r) { Nh[r] = Bn[od[r]]; Nl[r] = Bn[3072 + od[r]]; }
        }

        const unsigned* sb = &sG[ch & 1][0];
        #pragma unroll
        for (int si = 0; si < 12; ++si) {
            const int base = (si * 16 + l15) * 20 + q * 4;
            const u32x4 gh = *(const u32x4*)(sb + base);
            const u32x4 gl = *(const u32x4*)(sb + 3840 + base);
            tre[si] = mfma_bf16(gh, Ph, tre[si]);
            tre[si] = mfma_bf16(gh, Pl, tre[si]);
            tre[si] = mfma_bf16(gl, Ph, tre[si]);
            tim[si] = mfma_bf16(gh, Qh, tim[si]);
            tim[si] = mfma_bf16(gh, Ql, tim[si]);
            tim[si] = mfma_bf16(gl, Qh, tim[si]);
        }

        if (ch < 11) {
            // write targets buf[(ch+1)&1]; every wave in iter ch reads only
            // buf[ch&1]; stragglers in iter ch-1 are impossible past the
            // previous barrier -> no WAR. Single RAW barrier after the write.
            fw_stage_write(&sG[(ch + 1) & 1][0], tid, st);
            __syncthreads();
            #pragma unroll
            for (int r = 0; r < 4; ++r) { Wh[r] = Nh[r]; Wl[r] = Nl[r]; }
        }
    }

    float qr = 0.f, qi = 0.f;
    {
        float g = kx * 16.f; g -= rintf(g);
        const float rc = __builtin_amdgcn_cosf(g), rs = __builtin_amdgcn_sinf(g);
        #pragma unroll
        for (int rg = 0; rg < 4; ++rg) {
            const float ph = redphase(kxh, kxl, (float)(q * 4 + rg - 96));
            float c = __builtin_amdgcn_cosf(ph), s = __builtin_amdgcn_sinf(ph);
            #pragma unroll
            for (int si = 0; si < 12; ++si) {
                const float tr = tre[si][rg], ti = tim[si][rg];
                qr += c * tr + s * ti;
                qi += c * ti - s * tr;
                const float nc = c * rc - s * rs, ns = s * rc + c * rs;
                c = nc; s = ns;
            }
        }
    }
    qr += __shfl_xor(qr, 16); qi += __shfl_xor(qi, 16);
    qr += __shfl_xor(qr, 32); qi += __shfl_xor(qi, 32);
    if (lane < 16) {
        if (mode == 0) {
            const float den = fmaxf(sqrtf(qr * qr + qi * qi), 1e-20f);
            wre[m] /= den; wim[m] /= den;
        } else {
            const float sc = sqrtf(wre[m] * wre[m] + wim[m] * wim[m]);
            qre[m] = qr * sc; qim[m] = qi * sc;
        }
    }
}

// ---------------------------------------------------------------------------
__global__ void presplit_k(const float* __restrict__ re, const float* __restrict__ im,
                           unsigned* __restrict__ Gh, unsigned* __restrict__ Gl) {
    const int e = blockIdx.x * 256 + threadIdx.x;
    unsigned h, l;
    split_pk(re[e], im[e], h, l);     // low16 = re (even K), high16 = im (odd K)
    Gh[e] = h; Gl[e] = l;
}

// Reduce PG partial images + presplit (pipe path)
__global__ void presplitP_k(const float* __restrict__ outP,
                            unsigned* __restrict__ Gh, unsigned* __restrict__ Gl) {
    const int e = blockIdx.x * 256 + threadIdx.x;
    float re = 0.f, im = 0.f;
    #pragma unroll 8
    for (int g = 0; g < PG; ++g) {
        re += outP[(size_t)g * (2 * MTOT) + e];
        im += outP[(size_t)g * (2 * MTOT) + MTOT + e];
    }
    unsigned h, l;
    split_pk(re, im, h, l);
    Gh[e] = h; Gl[e] = l;
}

// Reduce PG partial images -> final output
__global__ void reduceOut_k(const float* __restrict__ outP, float* __restrict__ out) {
    const int e = blockIdx.x * 256 + threadIdx.x;
    float re = 0.f, im = 0.f;
    #pragma unroll 8
    for (int g = 0; g < PG; ++g) {
        re += outP[(size_t)g * (2 * MTOT) + e];
        im += outP[(size_t)g * (2 * MTOT) + MTOT + e];
    }
    out[e] = re; out[MTOT + e] = im;
}

// ---------------------------------------------------------------------------
extern "C" void kernel_launch(void* const* d_in, const int* in_sizes, int n_in,
                              void* d_out, int out_size, void* d_ws, size_t ws_size,
                              hipStream_t stream)
{
    const float* xin  = (const float*)d_in[0];   // (2,192,192)
    const float* traj = (const float*)d_in[1];   // (36864,2)
    float* out = (float*)d_out;                  // (2,192,192)

    char* pb = (char*)d_ws;
    unsigned* BS = (unsigned*)pb; pb += (size_t)2304 * 6144 * 4;   // 56.6 MB
    unsigned* ES = (unsigned*)pb; pb += (size_t)2304 * 6144 * 4;   // 56.6 MB
    float* outP = (float*)pb; pb += (size_t)PG * 2 * MTOT * 4;     // 18.9 MB
    float* wr   = (float*)pb; pb += MTOT * 4;
    float* wi   = (float*)pb; pb += MTOT * 4;
    float* dre  = (float*)pb; pb += MTOT * 4;
    float* dim_ = (float*)pb; pb += MTOT * 4;
    unsigned* Ghi = (unsigned*)pb; pb += MTOT * 4;
    unsigned* Glo = (unsigned*)pb; pb += MTOT * 4;

    precompP_k<<<dim3(MTOT / 256, NPIX), 256, 0, stream>>>(traj, 1, BS);
    winit_k<<<MTOT / 256, 256, 0, stream>>>(wr, wi);

    for (int it = 0; it < 3; ++it) {
        ebuild_k<<<dim3(MTOT / 256, NPIX), 256, 0, stream>>>(traj, wr, wi, ES);
        adj_gemm_k<<<9 * GRP, 256, 0, stream>>>(ES, BS, outP);
        presplitP_k<<<MTOT / 256, 256, 0, stream>>>(outP, Ghi, Glo);
        fwdq_k<<<256, 576, 0, stream>>>(traj, BS, Ghi, Glo, wr, wi, 0, dre, dim_);
    }

    presplit_k<<<MTOT / 256, 256, 0, stream>>>(xin, xin + MTOT, Ghi, Glo);
    fwdq_k<<<256, 576, 0, stream>>>(traj, BS, Ghi, Glo, wr, wi, 1, dre, dim_);
    ebuild_k<<<dim3(MTOT / 256, NPIX), 256, 0, stream>>>(traj, dre, dim_, ES);
    adj_gemm_k<<<9 * GRP, 256, 0, stream>>>(ES, BS, outP);
    reduceOut_k<<<MTOT / 256, 256, 0, stream>>>(outP, out);
}

// Round 17
// 443.185 us; speedup vs baseline: 1.0534x; 1.0534x over previous
//
#include <hip/hip_runtime.h>
#include <math.h>

// Radial NUFFT + Pipe-Menon density compensation, MI355X (gfx950).
// bf16 MFMA (16x16x32), 2-term hi/lo split (3 products). Round 31 = r29
// (best 456.5us) + adj SINGLE-BARRIER (r21's adj isolated: r20->r21 algebra
// shows it was ~-2us/dispatch, masked then by a fwdq regression). Race
// proof: each wave's lgkmcnt(0) (needed for its MFMAs) completes its reads
// of buf ch%3 BEFORE it can arrive at barrier(ch+1); STAGE(ch+3) which
// overwrites buf ch%3 is issued only after that barrier's rendezvous ->
// reads drained block-wide before any overwrite. 18 barriers deleted,
// LDS stays 48KB/3 blocks/CU (r30's 64KB occupancy loss avoided), stage
// flight = full phase. setprio(1) around MFMA cluster (T5 regime).
// + winit folded into precompP (one fewer dispatch gap).
// r30 lesson logged: 2-chunk phases raise MfmaUtil but cost 3->2 blocks/CU
// -> net loss; 1-chunk/3-bubuffer is the right corner.

#define MTOT 36864      // N_SHOTS*N_SAMPLES == NPIX*NPIX
#define NPIX 192
#define SPLITS 128
#define GRP 64                  // split-groups: block g covers splits {g, g+64}
#define NCH 36                  // 2 splits x 18 chunks of 16 m
#define PG 64                   // privatized partial images (one per group)

typedef __attribute__((ext_vector_type(8))) short s16x8;
typedef __attribute__((ext_vector_type(4))) float f32x4;
typedef __attribute__((ext_vector_type(4))) unsigned u32x4;

__device__ __forceinline__ f32x4 mfma_bf16(u32x4 a, u32x4 b, f32x4 c) {
    return __builtin_amdgcn_mfma_f32_16x16x32_bf16(
        __builtin_bit_cast(s16x8, a), __builtin_bit_cast(s16x8, b), c, 0, 0, 0);
}

// async 16B/lane global->LDS (DMA); LDS dest = wave-uniform base + lane*16.
__device__ __forceinline__ void g2l16(const void* g, void* l) {
    __builtin_amdgcn_global_load_lds(
        (const __attribute__((address_space(1))) void*)g,
        (__attribute__((address_space(3))) void*)l, 16, 0, 0);
}

// Split (a,b) into packed bf16 pairs: hi = (bf16(a) | bf16(b)<<16), lo = residuals.
__device__ __forceinline__ void split_pk(float a, float b, unsigned &hi, unsigned &lo) {
    const unsigned ua = __float_as_uint(a), ub = __float_as_uint(b);
    const unsigned ha = (ua + 0x8000u) & 0xffff0000u;
    const unsigned hb = (ub + 0x8000u) & 0xffff0000u;
    hi = (ha >> 16) | hb;
    const float la = a - __uint_as_float(ha);
    const float lb = b - __uint_as_float(hb);
    lo = ((__float_as_uint(la) + 0x8000u) >> 16) |
         ((__float_as_uint(lb) + 0x8000u) & 0xffff0000u);
}

// k split into 12-bit hi + residual so kh*p (p integer, |p|<=96) is EXACT in fp32.
__device__ __forceinline__ void ksplit(float k, float &kh, float &kl) {
    kh = __uint_as_float(__float_as_uint(k) & 0xfffff000u);
    kl = k - kh;
}
__device__ __forceinline__ float redphase(float kh, float kl, float p) {
    float r = kh * p;
    r -= rintf(r);
    r = fmaf(kl, p, r);
    return r;                   // revolutions, |r| <= ~0.512
}
__device__ __forceinline__ unsigned rot16(unsigned v) {
    return __builtin_amdgcn_alignbit(v, v, 16);
}
__device__ __forceinline__ int swz(int c) {        // bank swizzle (r10-verified)
    return ((c ^ (c >> 2)) & 3) << 2;
}

// ---------------------------------------------------------------------------
// Precompute packed B phasor (cos, -sin) hi/lo, chunk-contiguous + swizzled:
// PS[mc][plane][c(192)][mi^swz(c)]  (r10-verified layout). Also initializes
// w = 1 + 0i (folded winit: c==0 slice).
__global__ void precompP_k(const float* __restrict__ traj, const int comp,
                           unsigned* __restrict__ PS,
                           float* __restrict__ wr, float* __restrict__ wi) {
    const int m = blockIdx.x * 256 + threadIdx.x;
    const int c = blockIdx.y;
    if (c == 0) { wr[m] = 1.f; wi[m] = 0.f; }
    float kh, kl; ksplit(traj[2 * m + comp], kh, kl);
    const float ph = redphase(kh, kl, (float)(c - 96));
    const float co = __builtin_amdgcn_cosf(ph);
    const float si = __builtin_amdgcn_sinf(ph);
    unsigned h, l; split_pk(co, -si, h, l);
    const int mc = m >> 4, mi = (m & 15) ^ swz(c);
    PS[(size_t)mc * 6144 + c * 16 + mi]        = h;
    PS[(size_t)mc * 6144 + 3072 + c * 16 + mi] = l;
}

// E[m,x] = conj(A[m,x]) * d[m], packed bf16 hi/lo, same swizzled layout.
__global__ void ebuild_k(const float* __restrict__ traj,
                         const float* __restrict__ dr, const float* __restrict__ di,
                         unsigned* __restrict__ ES) {
    const int m = blockIdx.x * 256 + threadIdx.x;
    const int c = blockIdx.y;                        // x coordinate
    float kh, kl; ksplit(traj[2 * m], kh, kl);
    const float ph = redphase(kh, kl, (float)(c - 96));
    const float co = __builtin_amdgcn_cosf(ph);
    const float si = __builtin_amdgcn_sinf(ph);
    const float dr_ = dr[m], di_ = di[m];
    const float Er = co * dr_ - si * di_;
    const float Ei = co * di_ + si * dr_;
    unsigned h, l; split_pk(Er, Ei, h, l);
    const int mc = m >> 4, mi = (m & 15) ^ swz(c);
    ES[(size_t)mc * 6144 + c * 16 + mi]        = h;
    ES[(size_t)mc * 6144 + 3072 + c * 16 + mi] = l;
}

// ---------------------------------------------------------------------------
// Adjoint pure GEMM, single-barrier chunks: outP[g][x,y] =
// sum_{m in splits g,g+64} E[m,x]*conj(B[m,y]).
// 576 blocks (64 groups x 9 tiles) of 4 waves; block owns a 64x64 tile of
// image g EXCLUSIVELY -> plain stores, zero atomics. 3 LDS buffers; per
// chunk: counted vmcnt(4) -> ONE s_barrier -> issue STAGE(ch+2) -> ds_read
// frags -> lgkmcnt(0) -> setprio(1) 24xMFMA setprio(0). WAR proof in header.
__global__ __launch_bounds__(256) void adj_gemm_k(
    const unsigned* __restrict__ ES, const unsigned* __restrict__ BS,
    float* __restrict__ outP)
{
    __shared__ unsigned sAB[3][4096];              // 48 KB triple buffer
    const int tid = threadIdx.x;
    const int lane = tid & 63, wid = tid >> 6;     // wid 0..3
    const int l15 = lane & 15, qd = lane >> 4;
    const int L = blockIdx.x;                      // 0..575, XCD swizzle
    const int xcd = L & 7, j = L >> 3;             // j 0..71
    const int g = xcd * (GRP / 8) + j / 9;         // split-group 0..63
    const int tile = j % 9;
    const int bx = tile % 3, by = tile / 3;
    const int wi = wid & 1, wj = wid >> 1;
    const int x0 = bx * 64 + wi * 32, y0 = by * 64 + wj * 32;
    float* outRe = outP + (size_t)g * (2 * MTOT);
    float* outIm = outRe + MTOT;

    f32x4 accRe[2][2], accIm[2][2];
    #pragma unroll
    for (int i = 0; i < 2; ++i)
        #pragma unroll
        for (int j2 = 0; j2 < 2; ++j2) {
            accRe[i][j2] = (f32x4){0.f, 0.f, 0.f, 0.f};
            accIm[i][j2] = (f32x4){0.f, 0.f, 0.f, 0.f};
        }

    // staging: chunk c of this block = split (g + 64*(c>=18)), local chunk c%18
    const size_t g18 = (size_t)g * 18;
    const int exo = bx * 1024 + tid * 4;           // E rows [bx*64..+64)
    const int byo = by * 1024 + tid * 4;           // B rows [by*64..+64)
    #define STAGE(c, buf)                                                  \
    {                                                                      \
        const size_t id_ = (g18 + (c) + (((c) >= 18) ? 1134 : 0)) * 6144; \
        const unsigned* E0_ = ES + id_;                                    \
        const unsigned* B0_ = BS + id_;                                    \
        g2l16(E0_ + exo,        &sAB[buf][tid * 4]);                       \
        g2l16(E0_ + 3072 + exo, &sAB[buf][1024 + tid * 4]);                \
        g2l16(B0_ + byo,        &sAB[buf][2048 + tid * 4]);                \
        g2l16(B0_ + 3072 + byo, &sAB[buf][3072 + tid * 4]);                \
    }

    // fragment LDS word offsets within a buffer (local coord; swz(local)==swz(global))
    int eoff[2], boff[2];
    #pragma unroll
    for (int t = 0; t < 2; ++t) {
        const int cE = wi * 32 + t * 16 + l15;     // local x coord 0..63
        eoff[t] = cE * 16 + ((qd ^ ((cE ^ (cE >> 2)) & 3)) << 2);
        const int cB = wj * 32 + t * 16 + l15;     // local y coord 0..63
        boff[t] = 2048 + cB * 16 + ((qd ^ ((cB ^ (cB >> 2)) & 3)) << 2);
    }

    STAGE(0, 0);                                   // prologue: chunks 0,1
    STAGE(1, 1);

    int rb = 0;                                    // read buffer = ch % 3
    for (int ch = 0; ch < NCH; ++ch) {
        // wait for stage(ch); keep stage(ch+1) in flight
        if (ch + 1 < NCH) {
            asm volatile("s_waitcnt vmcnt(4)" ::: "memory");
        } else {
            asm volatile("s_waitcnt vmcnt(0)" ::: "memory");
        }
        __builtin_amdgcn_s_barrier();              // buf rb ready; prior reads drained
        if (ch + 2 < NCH) {                        // safe: WAR proof in header
            const int wb = (rb + 2 >= 3) ? rb - 1 : rb + 2;   // (ch+2)%3
            STAGE(ch + 2, wb);
        }

        const unsigned* sb = &sAB[rb][0];
        u32x4 Eh[2], El[2], PhA[2], PlA[2];
        #pragma unroll
        for (int t = 0; t < 2; ++t) {
            Eh[t]  = *(const u32x4*)(sb + eoff[t]);
            El[t]  = *(const u32x4*)(sb + 1024 + eoff[t]);
            PhA[t] = *(const u32x4*)(sb + boff[t]);
            PlA[t] = *(const u32x4*)(sb + 1024 + boff[t]);
        }
        asm volatile("s_waitcnt lgkmcnt(0)" ::: "memory");
        __builtin_amdgcn_sched_barrier(0);         // rule 18: pin MFMAs below
        __builtin_amdgcn_s_setprio(1);

        #pragma unroll
        for (int sj = 0; sj < 2; ++sj) {
            const u32x4 Ph = PhA[sj], Pl = PlA[sj];
            u32x4 Qh, Ql;
            #pragma unroll
            for (int r = 0; r < 4; ++r) {
                Qh[r] = rot16(Ph[r]) ^ 0x00008000u;                       // (sb, cb)
                Ql[r] = rot16(Pl[r]) ^ 0x00008000u;
            }
            #pragma unroll
            for (int si = 0; si < 2; ++si) {
                accRe[si][sj] = mfma_bf16(Eh[si], Ph, accRe[si][sj]);
                accRe[si][sj] = mfma_bf16(Eh[si], Pl, accRe[si][sj]);
                accRe[si][sj] = mfma_bf16(El[si], Ph, accRe[si][sj]);
                accIm[si][sj] = mfma_bf16(Eh[si], Qh, accIm[si][sj]);
                accIm[si][sj] = mfma_bf16(Eh[si], Ql, accIm[si][sj]);
                accIm[si][sj] = mfma_bf16(El[si], Qh, accIm[si][sj]);
            }
        }
        __builtin_amdgcn_s_setprio(0);
        rb = (rb + 1 == 3) ? 0 : rb + 1;
    }
    #undef STAGE

    // epilogue: PLAIN stores -- block exclusively owns tile (g, x0.., y0..)
    #pragma unroll
    for (int si = 0; si < 2; ++si)
        #pragma unroll
        for (int sj = 0; sj < 2; ++sj)
            #pragma unroll
            for (int rg = 0; rg < 4; ++rg) {
                const int x = x0 + si * 16 + qd * 4 + rg;   // C/D row
                const int y = y0 + sj * 16 + l15;           // C/D col
                outRe[x * NPIX + y] = accRe[si][sj][rg];
                outIm[x * NPIX + y] = accIm[si][sj][rg];
            }
}

// ---------------------------------------------------------------------------
// fwdq: q[m] = sum_x A[m,x] * (sum_y B[m,y]*g[x,y]).  r27 form (proven):
// B-phasors gathered from BS, single barrier per chunk, reg-staged dbuf.
__device__ __forceinline__ void fw_stage_load(const unsigned* __restrict__ Ghi,
                                              const unsigned* __restrict__ Glo,
                                              int tid, int koff, u32x4 st[3]) {
    #pragma unroll
    for (int j = 0; j < 3; ++j) {
        const int li = tid + j * 576;
        if (li < 1536) {
            const int row = li >> 3, pl = (li >> 2) & 1, qt = li & 3;
            const unsigned* src = pl ? Glo : Ghi;
            st[j] = *(const u32x4*)(src + row * 192 + koff + qt * 4);
        }
    }
}
__device__ __forceinline__ void fw_stage_write(unsigned* sb, int tid, const u32x4 st[3]) {
    #pragma unroll
    for (int j = 0; j < 3; ++j) {
        const int li = tid + j * 576;
        if (li < 1536) {
            const int row = li >> 3, pl = (li >> 2) & 1, qt = li & 3;
            *(u32x4*)(sb + pl * 3840 + row * 20 + qt * 4) = st[j];
        }
    }
}

__global__ __launch_bounds__(576) void fwdq_k(
    const float* __restrict__ traj, const unsigned* __restrict__ BS,
    const unsigned* __restrict__ Ghi, const unsigned* __restrict__ Glo,
    float* __restrict__ wre, float* __restrict__ wim,
    const int mode,
    float* __restrict__ qre, float* __restrict__ qim)
{
    __shared__ unsigned sG[2][2 * 3840];   // 60 KB
    const int tid = threadIdx.x;
    const int lane = tid & 63, wid = tid >> 6;         // wid 0..8
    const int l15 = lane & 15, q = lane >> 4;
    const int mc = blockIdx.x * 9 + wid;
    const int m = mc * 16 + l15;
    const float kx = traj[2 * m];
    float kxh, kxl;
    ksplit(kx, kxh, kxl);

    f32x4 tre[12], tim[12];
    #pragma unroll
    for (int i = 0; i < 12; ++i) {
        tre[i] = (f32x4){0.f, 0.f, 0.f, 0.f};
        tim[i] = (f32x4){0.f, 0.f, 0.f, 0.f};
    }

    // B-phasor gather offsets within the wave's BS mc-slice
    const unsigned* Bm = BS + (size_t)mc * 6144;
    int od[4];
    #pragma unroll
    for (int r = 0; r < 4; ++r)
        od[r] = (q * 4 + r) * 16 + (l15 ^ (((r ^ q) & 3) << 2));

    unsigned Wh[4], Wl[4];
    #pragma unroll
    for (int r = 0; r < 4; ++r) { Wh[r] = Bm[od[r]]; Wl[r] = Bm[3072 + od[r]]; }

    u32x4 st[3];
    fw_stage_load(Ghi, Glo, tid, 0, st);
    fw_stage_write(&sG[0][0], tid, st);
    __syncthreads();

    for (int ch = 0; ch < 12; ++ch) {
        if (ch < 11) fw_stage_load(Ghi, Glo, tid, (ch + 1) * 16, st);

        // phasors from precomputed W = (cos, -sin):
        u32x4 Ph, Pl, Qh, Ql;
        #pragma unroll
        for (int r = 0; r < 4; ++r) {
            Ph[r] = Wh[r] ^ 0x80000000u;     // (cos,  sin)
            Pl[r] = Wl[r] ^ 0x80000000u;
            Qh[r] = rot16(Wh[r]);            // (-sin, cos)
            Ql[r] = rot16(Wl[r]);
        }
        // prefetch next chunk's phasor words (use-distance = 72 MFMAs)
        unsigned Nh[4], Nl[4];
        if (ch < 11) {
            const unsigned* Bn = Bm + (ch + 1) * 256;
            #pragma unroll
            for (int r = 0; r < 4; ++r) { Nh[r] = Bn[od[r]]; Nl[r] = Bn[3072 + od[r]]; }
        }

        const unsigned* sb = &sG[ch & 1][0];
        #pragma unroll
        for (int si = 0; si < 12; ++si) {
            const int base = (si * 16 + l15) * 20 + q * 4;
            const u32x4 gh = *(const u32x4*)(sb + base);
            const u32x4 gl = *(const u32x4*)(sb + 3840 + base);
            tre[si] = mfma_bf16(gh, Ph, tre[si]);
            tre[si] = mfma_bf16(gh, Pl, tre[si]);
            tre[si] = mfma_bf16(gl, Ph, tre[si]);
            tim[si] = mfma_bf16(gh, Qh, tim[si]);
            tim[si] = mfma_bf16(gh, Ql, tim[si]);
            tim[si] = mfma_bf16(gl, Qh, tim[si]);
        }

        if (ch < 11) {
            // write targets buf[(ch+1)&1]; every wave in iter ch reads only
            // buf[ch&1]; stragglers in iter ch-1 are impossible past the
            // previous barrier -> no WAR. Single RAW barrier after the write.
            fw_stage_write(&sG[(ch + 1) & 1][0], tid, st);
            __syncthreads();
            #pragma unroll
            for (int r = 0; r < 4; ++r) { Wh[r] = Nh[r]; Wl[r] = Nl[r]; }
        }
    }

    float qr = 0.f, qi = 0.f;
    {
        float g = kx * 16.f; g -= rintf(g);
        const float rc = __builtin_amdgcn_cosf(g), rs = __builtin_amdgcn_sinf(g);
        #pragma unroll
        for (int rg = 0; rg < 4; ++rg) {
            const float ph = redphase(kxh, kxl, (float)(q * 4 + rg - 96));
            float c = __builtin_amdgcn_cosf(ph), s = __builtin_amdgcn_sinf(ph);
            #pragma unroll
            for (int si = 0; si < 12; ++si) {
                const float tr = tre[si][rg], ti = tim[si][rg];
                qr += c * tr + s * ti;
                qi += c * ti - s * tr;
                const float nc = c * rc - s * rs, ns = s * rc + c * rs;
                c = nc; s = ns;
            }
        }
    }
    qr += __shfl_xor(qr, 16); qi += __shfl_xor(qi, 16);
    qr += __shfl_xor(qr, 32); qi += __shfl_xor(qi, 32);
    if (lane < 16) {
        if (mode == 0) {
            const float den = fmaxf(sqrtf(qr * qr + qi * qi), 1e-20f);
            wre[m] /= den; wim[m] /= den;
        } else {
            const float sc = sqrtf(wre[m] * wre[m] + wim[m] * wim[m]);
            qre[m] = qr * sc; qim[m] = qi * sc;
        }
    }
}

// ---------------------------------------------------------------------------
__global__ void presplit_k(const float* __restrict__ re, const float* __restrict__ im,
                           unsigned* __restrict__ Gh, unsigned* __restrict__ Gl) {
    const int e = blockIdx.x * 256 + threadIdx.x;
    unsigned h, l;
    split_pk(re[e], im[e], h, l);     // low16 = re (even K), high16 = im (odd K)
    Gh[e] = h; Gl[e] = l;
}

// Reduce PG partial images + presplit (pipe path)
__global__ void presplitP_k(const float* __restrict__ outP,
                            unsigned* __restrict__ Gh, unsigned* __restrict__ Gl) {
    const int e = blockIdx.x * 256 + threadIdx.x;
    float re = 0.f, im = 0.f;
    #pragma unroll 8
    for (int g = 0; g < PG; ++g) {
        re += outP[(size_t)g * (2 * MTOT) + e];
        im += outP[(size_t)g * (2 * MTOT) + MTOT + e];
    }
    unsigned h, l;
    split_pk(re, im, h, l);
    Gh[e] = h; Gl[e] = l;
}

// Reduce PG partial images -> final output
__global__ void reduceOut_k(const float* __restrict__ outP, float* __restrict__ out) {
    const int e = blockIdx.x * 256 + threadIdx.x;
    float re = 0.f, im = 0.f;
    #pragma unroll 8
    for (int g = 0; g < PG; ++g) {
        re += outP[(size_t)g * (2 * MTOT) + e];
        im += outP[(size_t)g * (2 * MTOT) + MTOT + e];
    }
    out[e] = re; out[MTOT + e] = im;
}

// ---------------------------------------------------------------------------
extern "C" void kernel_launch(void* const* d_in, const int* in_sizes, int n_in,
                              void* d_out, int out_size, void* d_ws, size_t ws_size,
                              hipStream_t stream)
{
    const float* xin  = (const float*)d_in[0];   // (2,192,192)
    const float* traj = (const float*)d_in[1];   // (36864,2)
    float* out = (float*)d_out;                  // (2,192,192)

    char* pb = (char*)d_ws;
    unsigned* BS = (unsigned*)pb; pb += (size_t)2304 * 6144 * 4;   // 56.6 MB
    unsigned* ES = (unsigned*)pb; pb += (size_t)2304 * 6144 * 4;   // 56.6 MB
    float* outP = (float*)pb; pb += (size_t)PG * 2 * MTOT * 4;     // 18.9 MB
    float* wr   = (float*)pb; pb += MTOT * 4;
    float* wi   = (float*)pb; pb += MTOT * 4;
    float* dre  = (float*)pb; pb += MTOT * 4;
    float* dim_ = (float*)pb; pb += MTOT * 4;
    unsigned* Ghi = (unsigned*)pb; pb += MTOT * 4;
    unsigned* Glo = (unsigned*)pb; pb += MTOT * 4;

    precompP_k<<<dim3(MTOT / 256, NPIX), 256, 0, stream>>>(traj, 1, BS, wr, wi);

    for (int it = 0; it < 3; ++it) {
        ebuild_k<<<dim3(MTOT / 256, NPIX), 256, 0, stream>>>(traj, wr, wi, ES);
        adj_gemm_k<<<9 * GRP, 256, 0, stream>>>(ES, BS, outP);
        presplitP_k<<<MTOT / 256, 256, 0, stream>>>(outP, Ghi, Glo);
        fwdq_k<<<256, 576, 0, stream>>>(traj, BS, Ghi, Glo, wr, wi, 0, dre, dim_);
    }

    presplit_k<<<MTOT / 256, 256, 0, stream>>>(xin, xin + MTOT, Ghi, Glo);
    fwdq_k<<<256, 576, 0, stream>>>(traj, BS, Ghi, Glo, wr, wi, 1, dre, dim_);
    ebuild_k<<<dim3(MTOT / 256, NPIX), 256, 0, stream>>>(traj, dre, dim_, ES);
    adj_gemm_k<<<9 * GRP, 256, 0, stream>>>(ES, BS, outP);
    reduceOut_k<<<MTOT / 256, 256, 0, stream>>>(outP, out);
}